// Round 1
// baseline (216.452 us; speedup 1.0000x reference)
//
#include <hip/hip_runtime.h>

// KnowledgeEmbedding loss: 8 relations, each
//   ex = head[h]+rvec; pos = dot(ex, tail[t]) + bias[t]
//   neg_bn = dot(ex, tail[neg_n]) + bias[t]
//   loss += mean_b( softplus(-pos) + sum_n softplus(neg_bn) )
// Entire loss is one global sum over (rel, row, neg) terms / BATCH.

#define EMBED   100
#define NVEC    25      // float4 per embedding row
#define BATCH   4096
#define NUM_NEG 256

struct RelP {
    const float* head;
    const float* tail;
    const float* bias;
    int hc, tc;
};

struct Params {
    RelP rel[8];
    const float* rel_vecs;
    const int*   batch_idxs;
    const int*   neg_idxs;
    float*       out;
};

__device__ __forceinline__ float softplus_f(float x) {
    // softplus(x) = max(x,0) + log1p(exp(-|x|)); -log_sigmoid(x) == softplus(-x)
    float e = __expf(-fabsf(x));
    return fmaxf(x, 0.0f) + __logf(1.0f + e);
}

__launch_bounds__(256, 2)
__global__ void ke_loss_kernel(Params p) {
    const int bid    = blockIdx.x;
    const int r      = bid & 7;          // relation
    const int rowblk = (bid >> 3) & 15;  // 16 row-blocks of 256 rows
    const int chunk  = bid >> 7;         // 4 chunks of 64 negatives
    const int tid    = threadIdx.x;
    const int row    = rowblk * 256 + tid;

    const RelP rp = p.rel[r];
    const int h = p.batch_idxs[row * 8 + rp.hc];
    const int t = p.batch_idxs[row * 8 + rp.tc];

    const float4* __restrict__ hv = (const float4*)(rp.head + (size_t)h * EMBED);
    const float4* __restrict__ rv = (const float4*)(p.rel_vecs + r * EMBED);

    float4 ex[NVEC];
#pragma unroll
    for (int j = 0; j < NVEC; ++j) {
        const float4 a = hv[j];
        const float4 b = rv[j];
        ex[j] = make_float4(a.x + b.x, a.y + b.y, a.z + b.z, a.w + b.w);
    }

    const float bias_t = rp.bias[t];
    float acc = 0.0f;

    if (chunk == 0) {
        // positive term (once per row; chunk 0 only — wave-uniform branch)
        const float4* __restrict__ tv = (const float4*)(rp.tail + (size_t)t * EMBED);
        float d0 = 0.f, d1 = 0.f, d2 = 0.f, d3 = 0.f;
#pragma unroll
        for (int j = 0; j < NVEC; ++j) {
            const float4 v = tv[j];
            d0 = fmaf(ex[j].x, v.x, d0);
            d1 = fmaf(ex[j].y, v.y, d1);
            d2 = fmaf(ex[j].z, v.z, d2);
            d3 = fmaf(ex[j].w, v.w, d3);
        }
        const float pos = ((d0 + d1) + (d2 + d3)) + bias_t;
        acc += softplus_f(-pos);
    }

    // 64 negatives for this chunk; addresses are block-uniform (scalarizable)
    const int* __restrict__ negp = p.neg_idxs + r * NUM_NEG + chunk * 64;
#pragma unroll 2
    for (int n = 0; n < 64; ++n) {
        const int nidx = negp[n];
        const float4* __restrict__ nv = (const float4*)(rp.tail + (size_t)nidx * EMBED);
        float d0 = 0.f, d1 = 0.f, d2 = 0.f, d3 = 0.f;
#pragma unroll
        for (int j = 0; j < NVEC; ++j) {
            const float4 v = nv[j];
            d0 = fmaf(ex[j].x, v.x, d0);
            d1 = fmaf(ex[j].y, v.y, d1);
            d2 = fmaf(ex[j].z, v.z, d2);
            d3 = fmaf(ex[j].w, v.w, d3);
        }
        acc += softplus_f(((d0 + d1) + (d2 + d3)) + bias_t);
    }

    // wave reduce (wave64), then cross-wave via LDS, one atomic per block
#pragma unroll
    for (int off = 32; off > 0; off >>= 1)
        acc += __shfl_down(acc, off, 64);

    __shared__ float wsum[4];
    const int wid  = tid >> 6;
    const int lane = tid & 63;
    if (lane == 0) wsum[wid] = acc;
    __syncthreads();
    if (tid == 0) {
        const float s = (wsum[0] + wsum[1]) + (wsum[2] + wsum[3]);
        atomicAdd(p.out, s * (1.0f / BATCH));
    }
}

extern "C" void kernel_launch(void* const* d_in, const int* in_sizes, int n_in,
                              void* d_out, int out_size, void* d_ws, size_t ws_size,
                              hipStream_t stream) {
    const float* user  = (const float*)d_in[0];
    const float* prod  = (const float*)d_in[1];
    const float* word  = (const float*)d_in[2];
    const float* brand = (const float*)d_in[3];
    const float* cat   = (const float*)d_in[4];
    const float* rprod = (const float*)d_in[5];

    Params p;
    p.rel_vecs   = (const float*)d_in[6];
    p.batch_idxs = (const int*)d_in[15];
    p.neg_idxs   = (const int*)d_in[16];
    p.out        = (float*)d_out;

    p.rel[0] = {user, prod,  (const float*)d_in[7],  0, 1};  // purchase
    p.rel[1] = {user, word,  (const float*)d_in[8],  0, 2};  // mentions
    p.rel[2] = {prod, word,  (const float*)d_in[9],  1, 2};  // describe
    p.rel[3] = {prod, brand, (const float*)d_in[10], 1, 3};  // produced
    p.rel[4] = {prod, cat,   (const float*)d_in[11], 1, 4};  // belongs
    p.rel[5] = {prod, rprod, (const float*)d_in[12], 1, 5};  // also_bought
    p.rel[6] = {prod, rprod, (const float*)d_in[13], 1, 6};  // also_viewed
    p.rel[7] = {prod, rprod, (const float*)d_in[14], 1, 7};  // together

    hipMemsetAsync(d_out, 0, sizeof(float), stream);
    ke_loss_kernel<<<512, 256, 0, stream>>>(p);
}

// Round 2
// 178.808 us; speedup vs baseline: 1.2105x; 1.2105x over previous
//
#include <hip/hip_runtime.h>

// KnowledgeEmbedding loss as 8 fused fp32 GEMMs (M=4096, N=256, K=100) with
// softplus-sum epilogue, plus a small positive-term kernel.
// score(row,neg) = dot(head[h_row]+rvec, tail[neg]) + bias[t_row]
// loss = (1/B) * sum_rel [ sum_row softplus(-pos_row) + sum_{row,neg} softplus(score) ]

#define EMBED   100
#define BATCH   4096
#define NUM_NEG 256
#define KC      20    // K-chunk (float4-aligned into 100-float rows)
#define BM      64    // rows per block
#define BN      128   // negs per block
#define TM      4     // rows per thread
#define TN      8     // negs per thread

struct RelP {
    const float* head;
    const float* tail;
    const float* bias;
    int hc, tc;
};

struct Params {
    RelP rel[8];
    const float* rel_vecs;
    const int*   batch_idxs;
    const int*   neg_idxs;
    float*       out;
};

__device__ __forceinline__ float softplus_f(float x) {
    // softplus(x) = max(x,0) + log1p(exp(-|x|))
    float e = __expf(-fabsf(x));
    return fmaxf(x, 0.0f) + __logf(1.0f + e);
}

__device__ __forceinline__ float block_reduce_atomic(float v, float* out) {
    // wave64 reduce, then cross-wave via LDS, one atomic per block
#pragma unroll
    for (int off = 32; off > 0; off >>= 1)
        v += __shfl_down(v, off, 64);
    __shared__ float wsum[4];
    const int wid  = threadIdx.x >> 6;
    const int lane = threadIdx.x & 63;
    if (lane == 0) wsum[wid] = v;
    __syncthreads();
    if (threadIdx.x == 0) {
        const float s = (wsum[0] + wsum[1]) + (wsum[2] + wsum[3]);
        atomicAdd(out, s * (1.0f / BATCH));
    }
    return v;
}

__launch_bounds__(256, 4)
__global__ void ke_neg_kernel(Params p) {
    // grid: 8 rel * 64 rowblocks * 2 negblocks = 1024 blocks
    const int bid = blockIdx.x;
    const int r   = bid & 7;
    const int rb  = (bid >> 3) & 63;
    const int nb  = bid >> 9;            // 0..1
    const int tid = threadIdx.x;
    const int tx  = tid & 15;            // row group  (rows tx*4 .. +3)
    const int ty  = tid >> 4;            // neg group  (negs ty*8 .. +7)

    __shared__ float As[KC * BM];        // [k][row], ex = head+rvec fused
    __shared__ float Bs[KC * BN];        // [k][neg]

    const RelP rp = p.rel[r];

    // ---- staging assignments (fixed across k-chunks; hoist index gathers) ----
    // A: 64 rows x 5 float4 = 320 items. item f: row = f&63, j = f>>6
    const int arow0 = tid & 63;
    const int aj0   = tid >> 6;                       // 0..3
    const int h0    = p.batch_idxs[(rb * BM + arow0) * 8 + rp.hc];
    const float* aptr0 = rp.head + (size_t)h0 * EMBED + aj0 * 4;
    const float* rvp0  = p.rel_vecs + r * EMBED + aj0 * 4;
    const bool  doA1 = (tid < 320 - 256);             // tid < 64 -> row=tid, j=4
    const int   h1   = doA1 ? p.batch_idxs[(rb * BM + tid) * 8 + rp.hc] : 0;
    const float* aptr1 = rp.head + (size_t)h1 * EMBED + 16;
    const float* rvp1  = p.rel_vecs + r * EMBED + 16;

    // B: 128 negs x 5 float4 = 640 items. item f: neg = f&127, j = f>>7
    const int bneg0 = tid & 127;
    const int bj0   = tid >> 7;                       // 0..1  (f=tid)
    const int bj1   = bj0 + 2;                        // 2..3  (f=tid+256)
    const int n0    = p.neg_idxs[r * NUM_NEG + nb * BN + bneg0];
    const float* bptr0 = rp.tail + (size_t)n0 * EMBED + bj0 * 4;
    const float* bptr1 = rp.tail + (size_t)n0 * EMBED + bj1 * 4;
    const bool  doB2 = (tid < 640 - 512);             // tid < 128 -> neg=tid, j=4
    const int   n2   = doB2 ? p.neg_idxs[r * NUM_NEG + nb * BN + tid] : 0;
    const float* bptr2 = rp.tail + (size_t)n2 * EMBED + 16;

    float acc[TM * TN];
#pragma unroll
    for (int i = 0; i < TM * TN; ++i) acc[i] = 0.0f;

#pragma unroll
    for (int kc = 0; kc < EMBED / KC; ++kc) {
        const int k0 = kc * KC;

        // ---- stage A (ex = head + rvec), transposed [k][row] ----
        {
            const float4 a  = *(const float4*)(aptr0 + k0);
            const float4 rv = *(const float4*)(rvp0 + k0);
            const int kbase = aj0 * 4;
            As[(kbase + 0) * BM + arow0] = a.x + rv.x;
            As[(kbase + 1) * BM + arow0] = a.y + rv.y;
            As[(kbase + 2) * BM + arow0] = a.z + rv.z;
            As[(kbase + 3) * BM + arow0] = a.w + rv.w;
        }
        if (doA1) {
            const float4 a  = *(const float4*)(aptr1 + k0);
            const float4 rv = *(const float4*)(rvp1 + k0);
            As[16 * BM + tid] = a.x + rv.x;
            As[17 * BM + tid] = a.y + rv.y;
            As[18 * BM + tid] = a.z + rv.z;
            As[19 * BM + tid] = a.w + rv.w;
        }
        // ---- stage B, transposed [k][neg] ----
        {
            const float4 b = *(const float4*)(bptr0 + k0);
            const int kbase = bj0 * 4;
            Bs[(kbase + 0) * BN + bneg0] = b.x;
            Bs[(kbase + 1) * BN + bneg0] = b.y;
            Bs[(kbase + 2) * BN + bneg0] = b.z;
            Bs[(kbase + 3) * BN + bneg0] = b.w;
        }
        {
            const float4 b = *(const float4*)(bptr1 + k0);
            const int kbase = bj1 * 4;
            Bs[(kbase + 0) * BN + bneg0] = b.x;
            Bs[(kbase + 1) * BN + bneg0] = b.y;
            Bs[(kbase + 2) * BN + bneg0] = b.z;
            Bs[(kbase + 3) * BN + bneg0] = b.w;
        }
        if (doB2) {
            const float4 b = *(const float4*)(bptr2 + k0);
            Bs[16 * BN + tid] = b.x;
            Bs[17 * BN + tid] = b.y;
            Bs[18 * BN + tid] = b.z;
            Bs[19 * BN + tid] = b.w;
        }
        __syncthreads();

        // ---- inner product over this k-chunk ----
#pragma unroll 4
        for (int k = 0; k < KC; ++k) {
            const float4 a  = *(const float4*)&As[k * BM + tx * TM];
            const float4 b0 = *(const float4*)&Bs[k * BN + ty * TN];
            const float4 b1 = *(const float4*)&Bs[k * BN + ty * TN + 4];
            const float av[4] = {a.x, a.y, a.z, a.w};
            const float bv[8] = {b0.x, b0.y, b0.z, b0.w, b1.x, b1.y, b1.z, b1.w};
#pragma unroll
            for (int i = 0; i < TM; ++i)
#pragma unroll
                for (int n = 0; n < TN; ++n)
                    acc[i * TN + n] = fmaf(av[i], bv[n], acc[i * TN + n]);
        }
        __syncthreads();
    }

    // ---- epilogue: bias + softplus + sum ----
    float local = 0.0f;
#pragma unroll
    for (int i = 0; i < TM; ++i) {
        const int grow = rb * BM + tx * TM + i;
        const int t    = p.batch_idxs[grow * 8 + rp.tc];
        const float bias = rp.bias[t];
#pragma unroll
        for (int n = 0; n < TN; ++n)
            local += softplus_f(acc[i * TN + n] + bias);
    }
    block_reduce_atomic(local, p.out);
}

__launch_bounds__(256, 4)
__global__ void ke_pos_kernel(Params p) {
    // grid: 8 rel * 16 rowblocks = 128 blocks; one row per thread
    const int r      = blockIdx.x & 7;
    const int rowblk = blockIdx.x >> 3;
    const int tid    = threadIdx.x;
    const int row    = rowblk * 256 + tid;

    const RelP rp = p.rel[r];
    const int h = p.batch_idxs[row * 8 + rp.hc];
    const int t = p.batch_idxs[row * 8 + rp.tc];

    const float4* __restrict__ hv = (const float4*)(rp.head + (size_t)h * EMBED);
    const float4* __restrict__ rv = (const float4*)(p.rel_vecs + r * EMBED);
    const float4* __restrict__ tv = (const float4*)(rp.tail + (size_t)t * EMBED);

    float d0 = 0.f, d1 = 0.f, d2 = 0.f, d3 = 0.f;
#pragma unroll
    for (int j = 0; j < EMBED / 4; ++j) {
        const float4 a = hv[j];
        const float4 b = rv[j];
        const float4 v = tv[j];
        d0 = fmaf(a.x + b.x, v.x, d0);
        d1 = fmaf(a.y + b.y, v.y, d1);
        d2 = fmaf(a.z + b.z, v.z, d2);
        d3 = fmaf(a.w + b.w, v.w, d3);
    }
    const float pos = ((d0 + d1) + (d2 + d3)) + rp.bias[t];
    block_reduce_atomic(softplus_f(-pos), p.out);
}

extern "C" void kernel_launch(void* const* d_in, const int* in_sizes, int n_in,
                              void* d_out, int out_size, void* d_ws, size_t ws_size,
                              hipStream_t stream) {
    const float* user  = (const float*)d_in[0];
    const float* prod  = (const float*)d_in[1];
    const float* word  = (const float*)d_in[2];
    const float* brand = (const float*)d_in[3];
    const float* cat   = (const float*)d_in[4];
    const float* rprod = (const float*)d_in[5];

    Params p;
    p.rel_vecs   = (const float*)d_in[6];
    p.batch_idxs = (const int*)d_in[15];
    p.neg_idxs   = (const int*)d_in[16];
    p.out        = (float*)d_out;

    p.rel[0] = {user, prod,  (const float*)d_in[7],  0, 1};  // purchase
    p.rel[1] = {user, word,  (const float*)d_in[8],  0, 2};  // mentions
    p.rel[2] = {prod, word,  (const float*)d_in[9],  1, 2};  // describe
    p.rel[3] = {prod, brand, (const float*)d_in[10], 1, 3};  // produced
    p.rel[4] = {prod, cat,   (const float*)d_in[11], 1, 4};  // belongs
    p.rel[5] = {prod, rprod, (const float*)d_in[12], 1, 5};  // also_bought
    p.rel[6] = {prod, rprod, (const float*)d_in[13], 1, 6};  // also_viewed
    p.rel[7] = {prod, rprod, (const float*)d_in[14], 1, 7};  // together

    hipMemsetAsync(d_out, 0, sizeof(float), stream);
    ke_pos_kernel<<<128, 256, 0, stream>>>(p);
    ke_neg_kernel<<<1024, 256, 0, stream>>>(p);
}